// Round 9
// baseline (115.216 us; speedup 1.0000x reference)
//
#include <hip/hip_runtime.h>
#include <math.h>

#define KCONST 0.1f
#define GAMMA_C 1.0f
#define D_DIM 128

typedef __attribute__((ext_vector_type(8))) short bf16x8;
typedef __attribute__((ext_vector_type(4))) float f32x4;

#define ASYNC_COPY16(gsrc, ldst)                                                  \
  __builtin_amdgcn_global_load_lds(                                               \
      (const __attribute__((address_space(1))) void*)(gsrc),                      \
      (__attribute__((address_space(3))) void*)(ldst), 16, 0, 0)

__device__ __forceinline__ unsigned short f2bf(float f) {
  unsigned int u = __float_as_uint(f);
  u += 0x7fffu + ((u >> 16) & 1u);  // round-to-nearest-even
  return (unsigned short)(u >> 16);
}

// ---------------------------------------------------------------------------
// prep_x: 256 blocks. Converts x->bf16, writes nx2p[row]=1+||x||^2, per-block
// partial col-sums + sum(nx2). Block 0 zeroes out[0] (harness re-poisons it).
// ---------------------------------------------------------------------------
__global__ void prep_x(const float* __restrict__ x, unsigned short* __restrict__ xb,
                       float* __restrict__ nx2p, float* __restrict__ pSumX,
                       float* __restrict__ pS2, float* __restrict__ out_zero, int N) {
  if (blockIdx.x == 0 && threadIdx.x == 0) *out_zero = 0.f;
  const int tid = threadIdx.x;
  const int l = tid & 63, w = tid >> 6;
  const int l16 = l & 15, sub = l >> 4;
  const int waveId = blockIdx.x * 4 + w;  // 0..1023
  const float4* x4 = (const float4*)x;
  ushort4* xb4 = (ushort4*)xb;
  float4 c0 = {0.f, 0.f, 0.f, 0.f}, c1 = {0.f, 0.f, 0.f, 0.f};
  float s2 = 0.f;
#pragma unroll
  for (int it = 0; it < 4; ++it) {
    int row = (waveId + it * 1024) * 4 + sub;
    float4 v0 = x4[row * 32 + l16];
    float4 v1 = x4[row * 32 + 16 + l16];
    c0.x += v0.x; c0.y += v0.y; c0.z += v0.z; c0.w += v0.w;
    c1.x += v1.x; c1.y += v1.y; c1.z += v1.z; c1.w += v1.w;
    ushort4 b0, b1;
    b0.x = f2bf(v0.x); b0.y = f2bf(v0.y); b0.z = f2bf(v0.z); b0.w = f2bf(v0.w);
    b1.x = f2bf(v1.x); b1.y = f2bf(v1.y); b1.z = f2bf(v1.z); b1.w = f2bf(v1.w);
    xb4[row * 32 + l16] = b0;
    xb4[row * 32 + 16 + l16] = b1;
    float sq = v0.x * v0.x;
    sq = fmaf(v0.y, v0.y, sq); sq = fmaf(v0.z, v0.z, sq); sq = fmaf(v0.w, v0.w, sq);
    sq = fmaf(v1.x, v1.x, sq); sq = fmaf(v1.y, v1.y, sq);
    sq = fmaf(v1.z, v1.z, sq); sq = fmaf(v1.w, v1.w, sq);
    sq += __shfl_down(sq, 8); sq += __shfl_down(sq, 4);
    sq += __shfl_down(sq, 2); sq += __shfl_down(sq, 1);
    if (l16 == 0) {
      nx2p[row] = 1.f + sq;
      s2 += sq;
    }
  }
  // s2 lives at lanes {0,16,32,48}
  s2 += __shfl_down(s2, 16);
  s2 += __shfl_down(s2, 32);
  __shared__ float cs[128];
  __shared__ float s2w[4];
  if (tid < 128) cs[tid] = 0.f;
  if (l == 0) s2w[w] = s2;
  __syncthreads();
  atomicAdd(&cs[l16 * 4 + 0], c0.x); atomicAdd(&cs[l16 * 4 + 1], c0.y);
  atomicAdd(&cs[l16 * 4 + 2], c0.z); atomicAdd(&cs[l16 * 4 + 3], c0.w);
  atomicAdd(&cs[64 + l16 * 4 + 0], c1.x); atomicAdd(&cs[64 + l16 * 4 + 1], c1.y);
  atomicAdd(&cs[64 + l16 * 4 + 2], c1.z); atomicAdd(&cs[64 + l16 * 4 + 3], c1.w);
  __syncthreads();
  if (tid < 128) pSumX[blockIdx.x * 128 + tid] = cs[tid];
  if (tid == 0) pS2[blockIdx.x] = s2w[0] + s2w[1] + s2w[2] + s2w[3];
}

// ---------------------------------------------------------------------------
// merge_sums: 1 block x 1024 threads; 8-way segmented unrolled loads (MLP).
// ---------------------------------------------------------------------------
__global__ void merge_sums(const float* __restrict__ pSumX, const float* __restrict__ pS2,
                           float* __restrict__ sum_x, float* __restrict__ sum_nx2) {
  __shared__ float seg[8][128];
  __shared__ float s2w[4];
  const int t = threadIdx.x;       // 0..1023
  const int col = t & 127;
  const int sg = t >> 7;           // 0..7
  float s = 0.f;
#pragma unroll
  for (int b = 0; b < 32; ++b) s += pSumX[(sg * 32 + b) * 128 + col];
  seg[sg][col] = s;
  float s2 = (t < 256) ? pS2[t] : 0.f;
  if (t < 256) {
#pragma unroll
    for (int off = 32; off; off >>= 1) s2 += __shfl_down(s2, off);
    if ((t & 63) == 0) s2w[t >> 6] = s2;
  }
  __syncthreads();
  if (t < 128) {
    float r = 0.f;
#pragma unroll
    for (int k = 0; k < 8; ++k) r += seg[k][col];
    sum_x[t] = r;
  }
  if (t == 0) sum_nx2[0] = s2w[0] + s2w[1] + s2w[2] + s2w[3];
}

// ---------------------------------------------------------------------------
// prep_p: wave-per-row. Converts p->bf16; packs colc[j] =
// (Ac=(1+np2)*cfi, Bc=np2*cfi, np2, Tc=np2/(1+np2)); psiA[j] = psi.
// ---------------------------------------------------------------------------
__global__ void prep_p(const float* __restrict__ p, unsigned short* __restrict__ pb,
                       const float* __restrict__ sum_x, const float* __restrict__ sum_nx2,
                       float4* __restrict__ colc, float* __restrict__ psiA,
                       int M, int N) {
  const int lane = threadIdx.x & 63;
  const int wave = threadIdx.x >> 6;
  const int j = blockIdx.x * 4 + wave;
  if (j >= M) return;
  const float2* p2 = (const float2*)p;
  ushort2* pb2 = (ushort2*)pb;
  float2 v = p2[j * 64 + lane];
  ushort2 b;
  b.x = f2bf(v.x);
  b.y = f2bf(v.y);
  pb2[j * 64 + lane] = b;
  float np2 = fmaf(v.x, v.x, v.y * v.y);
  float sd = fmaf(v.x, sum_x[2 * lane], v.y * sum_x[2 * lane + 1]);
#pragma unroll
  for (int off = 32; off; off >>= 1) {
    np2 += __shfl_down(np2, off);
    sd += __shfl_down(sd, off);
  }
  if (lane == 0) {
    float ssd = *sum_nx2 + (float)N * np2 - 2.f * sd;
    float npn = sqrtf(np2);
    float cfi = 1.f / (npn * sqrtf(ssd));
    float4 cc;
    cc.x = (1.f + np2) * cfi;
    cc.y = np2 * cfi;
    cc.z = np2;
    cc.w = np2 / (1.f + np2);
    colc[j] = cc;
    psiA[j] = asinf(KCONST * (1.f - np2) / npn);
  }
}

// ---------------------------------------------------------------------------
// pair_mfma v3 (hybrid): 128x128 tile/block, 4 waves in 2x2 quadrants.
// A-tile (xs, 32 KB) staged via XOR-swizzled global_load_lds (latency batched
// behind one barrier, 4 blocks/CU co-resident to overlap). B-fragments loaded
// DIRECT from global: pb is 0.5 MB -> resident in every XCD L2 (short
// latency, hidden by 16 waves/CU). Exact early-out epilogue; block partial
// folded into out via no-return atomicAdd (out zeroed by prep_x).
// ---------------------------------------------------------------------------
__global__ __launch_bounds__(256, 4) void pair_mfma(
    const unsigned short* __restrict__ xb, const unsigned short* __restrict__ pb,
    const int* __restrict__ labels, const float* __restrict__ nx2p,
    const float4* __restrict__ colc, const float* __restrict__ psiA,
    float* __restrict__ out, float invN) {
  __shared__ float4 xs4[2048];  // 128 rows x 16 quads (quad = 8 bf16), swizzled
  __shared__ float wred[4];

  const int tid = threadIdx.x;
  const int l = tid & 63;
  const int w = tid >> 6;
  const int row0 = blockIdx.y * 128;
  const int col0 = blockIdx.x * 128;
  const float4* xg = (const float4*)(xb + (size_t)row0 * D_DIM);

  // stage A: 32 wave-issues of 64 quads; slot (r,ql) <- source quad (r, ql^(r&15))
#pragma unroll
  for (int ci = w; ci < 32; ci += 4) {
    int qi = ci * 64 + l;
    int r = qi >> 4, ql = qi & 15;
    int srcq = r * 16 + (ql ^ (r & 15));
    ASYNC_COPY16(xg + srcq, xs4 + ci * 64);
  }
  __syncthreads();

  const int m = tid & 15;
  const int q = (tid >> 4) & 3;
  const int wr = (w & 1) * 64;   // wave's row offset within tile
  const int wc = (w >> 1) * 64;  // wave's col offset within tile
  const float4* pg = (const float4*)(pb + (size_t)(col0 + wc) * D_DIM);

  f32x4 acc[4][4];
#pragma unroll
  for (int r = 0; r < 4; ++r)
#pragma unroll
    for (int c = 0; c < 4; ++c) acc[r][c] = (f32x4)(0.f);

#pragma unroll
  for (int s = 0; s < 4; ++s) {
    const int qphys = (s * 4 + q) ^ m;  // logical quad s*4+q at row low bits m
    bf16x8 a[4], b[4];
#pragma unroll
    for (int c = 0; c < 4; ++c)
      b[c] = __builtin_bit_cast(bf16x8, pg[(c * 16 + m) * 16 + s * 4 + q]);
#pragma unroll
    for (int r = 0; r < 4; ++r)
      a[r] = __builtin_bit_cast(bf16x8, xs4[(wr + r * 16 + m) * 16 + qphys]);
#pragma unroll
    for (int r = 0; r < 4; ++r)
#pragma unroll
      for (int c = 0; c < 4; ++c)
        acc[r][c] = __builtin_amdgcn_mfma_f32_16x16x32_bf16(a[r], b[c], acc[r][c], 0, 0, 0);
  }

  // ---- fused epilogue with exact early-out ----
  float4 cc[4];
  int cols[4];
#pragma unroll
  for (int c = 0; c < 4; ++c) {
    cols[c] = col0 + wc + c * 16 + m;
    cc[c] = colc[cols[c]];  // (Ac, Bc, np2, Tc)
  }
  float4 rnp4v[4];
  int4 lb4v[4];
#pragma unroll
  for (int r = 0; r < 4; ++r) {
    rnp4v[r] = *(const float4*)&nx2p[row0 + wr + r * 16 + q * 4];  // 1+nx2
    lb4v[r] = *(const int4*)&labels[row0 + wr + r * 16 + q * 4];
  }

  float ssum = 0.f;
#pragma unroll
  for (int r = 0; r < 4; ++r) {
    const f32x4 rnp4 = __builtin_bit_cast(f32x4, rnp4v[r]);
    const int4 lb4 = lb4v[r];
#pragma unroll
    for (int c = 0; c < 4; ++c) {
      const f32x4 dv = acc[r][c];
      const float Tc = cc[c].w;
      // e_g > 0  <=>  nump_g > 0  (necessary for any neg contribution)
      float e0 = fmaf(-Tc, rnp4[0], dv[0]);
      float e1 = fmaf(-Tc, rnp4[1], dv[1]);
      float e2 = fmaf(-Tc, rnp4[2], dv[2]);
      float e3 = fmaf(-Tc, rnp4[3], dv[3]);
      float hm = fmaxf(fmaxf(e0, e1), fmaxf(e2, e3));
      bool h = (hm > 0.f) | (cols[c] == lb4.x) | (cols[c] == lb4.y) |
               (cols[c] == lb4.z) | (cols[c] == lb4.w);
      if (__builtin_expect(h, 0)) {
        const float psi = psiA[cols[c]];
        const float C1 = 1.f + psi;
        const float omnp2 = 1.f - cc[c].z;
#pragma unroll
        for (int g = 0; g < 4; ++g) {
          float rnp = rnp4[g];
          float dot = dv[g];
          int lb = (g == 0) ? lb4.x : (g == 1) ? lb4.y : (g == 2) ? lb4.z : lb4.w;
          float den2 = fmaf(cc[c].z, rnp, omnp2) - 2.f * dot;
          float nump = fmaf(dot, cc[c].x, -cc[c].y * rnp);
          float u = nump * __builtin_amdgcn_rsqf(den2);
          u = __builtin_amdgcn_fmed3f(u, -1.f, 1.f);
          float ax = fabsf(u);
          float rt = __builtin_amdgcn_sqrtf(1.f - ax);
          float poly = fmaf(fmaf(fmaf(-0.0187293f, ax, 0.0742610f), ax, -0.2121144f),
                            ax, 1.5707288f);
          float ac = rt * poly;
          ac = (u >= 0.f) ? ac : 3.14159265358979f - ac;
          float neg = __builtin_amdgcn_fmed3f(C1 - ac, 0.f, 1.f);
          float pos = fmaxf(0.f, ac - psi);
          ssum += (cols[c] == lb) ? pos : neg;
        }
      }
    }
  }

#pragma unroll
  for (int off = 32; off; off >>= 1) ssum += __shfl_down(ssum, off);
  if (l == 0) wred[w] = ssum;
  __syncthreads();
  if (tid == 0)
    atomicAdd(out, (wred[0] + wred[1] + wred[2] + wred[3]) * invN);
}

extern "C" void kernel_launch(void* const* d_in, const int* in_sizes, int n_in,
                              void* d_out, int out_size, void* d_ws, size_t ws_size,
                              hipStream_t stream) {
  const float* x = (const float*)d_in[0];
  const float* p = (const float*)d_in[1];
  const int* labels = (const int*)d_in[2];
  float* out = (float*)d_out;
  const int N = in_sizes[2];          // 16384
  const int M = in_sizes[1] / D_DIM;  // 2048

  float* ws = (float*)d_ws;
  float* nx2p = ws;                                  // N  (1 + ||x||^2)
  float4* colc = (float4*)(ws + N);                  // M float4
  float* psiA = ws + N + 4 * M;                      // M
  unsigned short* xb = (unsigned short*)(ws + N + 5 * M);            // N*128 bf16
  unsigned short* pb = (unsigned short*)(ws + N + 5 * M + 64 * N);   // M*128 bf16
  float* pSumX = ws + N + 5 * M + 64 * N + 64 * M;   // 256*128
  float* pS2 = pSumX + 256 * 128;                    // 256
  float* sum_x = pS2 + 256;                          // 128
  float* sum_nx2 = sum_x + 128;                      // 4

  prep_x<<<256, 256, 0, stream>>>(x, xb, nx2p, pSumX, pS2, out, N);
  merge_sums<<<1, 1024, 0, stream>>>(pSumX, pS2, sum_x, sum_nx2);
  prep_p<<<M / 4, 256, 0, stream>>>(p, pb, sum_x, sum_nx2, colc, psiA, M, N);

  dim3 grid(M / 128, N / 128);
  pair_mfma<<<grid, 256, 0, stream>>>(xb, pb, labels, nx2p, colc, psiA, out,
                                      1.0f / (float)N);
}

// Round 10
// 103.231 us; speedup vs baseline: 1.1161x; 1.1161x over previous
//
#include <hip/hip_runtime.h>
#include <math.h>

#define KCONST 0.1f
#define GAMMA_C 1.0f
#define D_DIM 128

typedef __attribute__((ext_vector_type(8))) short bf16x8;
typedef __attribute__((ext_vector_type(4))) float f32x4;

#define ASYNC_COPY16(gsrc, ldst)                                                  \
  __builtin_amdgcn_global_load_lds(                                               \
      (const __attribute__((address_space(1))) void*)(gsrc),                      \
      (__attribute__((address_space(3))) void*)(ldst), 16, 0, 0)

__device__ __forceinline__ unsigned short f2bf(float f) {
  unsigned int u = __float_as_uint(f);
  u += 0x7fffu + ((u >> 16) & 1u);  // round-to-nearest-even
  return (unsigned short)(u >> 16);
}

// ---------------------------------------------------------------------------
// prep_x: 256 blocks. Converts x->bf16, writes nx2p[row]=1+||x||^2, per-block
// partial col-sums + sum(nx2). Block 0 zeroes out[0].
// ---------------------------------------------------------------------------
__global__ void prep_x(const float* __restrict__ x, unsigned short* __restrict__ xb,
                       float* __restrict__ nx2p, float* __restrict__ pSumX,
                       float* __restrict__ pS2, float* __restrict__ out_zero, int N) {
  if (blockIdx.x == 0 && threadIdx.x == 0) *out_zero = 0.f;
  const int tid = threadIdx.x;
  const int l = tid & 63, w = tid >> 6;
  const int l16 = l & 15, sub = l >> 4;
  const int waveId = blockIdx.x * 4 + w;  // 0..1023
  const float4* x4 = (const float4*)x;
  ushort4* xb4 = (ushort4*)xb;
  float4 c0 = {0.f, 0.f, 0.f, 0.f}, c1 = {0.f, 0.f, 0.f, 0.f};
  float s2 = 0.f;
#pragma unroll
  for (int it = 0; it < 4; ++it) {
    int row = (waveId + it * 1024) * 4 + sub;
    float4 v0 = x4[row * 32 + l16];
    float4 v1 = x4[row * 32 + 16 + l16];
    c0.x += v0.x; c0.y += v0.y; c0.z += v0.z; c0.w += v0.w;
    c1.x += v1.x; c1.y += v1.y; c1.z += v1.z; c1.w += v1.w;
    ushort4 b0, b1;
    b0.x = f2bf(v0.x); b0.y = f2bf(v0.y); b0.z = f2bf(v0.z); b0.w = f2bf(v0.w);
    b1.x = f2bf(v1.x); b1.y = f2bf(v1.y); b1.z = f2bf(v1.z); b1.w = f2bf(v1.w);
    xb4[row * 32 + l16] = b0;
    xb4[row * 32 + 16 + l16] = b1;
    float sq = v0.x * v0.x;
    sq = fmaf(v0.y, v0.y, sq); sq = fmaf(v0.z, v0.z, sq); sq = fmaf(v0.w, v0.w, sq);
    sq = fmaf(v1.x, v1.x, sq); sq = fmaf(v1.y, v1.y, sq);
    sq = fmaf(v1.z, v1.z, sq); sq = fmaf(v1.w, v1.w, sq);
    sq += __shfl_down(sq, 8); sq += __shfl_down(sq, 4);
    sq += __shfl_down(sq, 2); sq += __shfl_down(sq, 1);
    if (l16 == 0) {
      nx2p[row] = 1.f + sq;
      s2 += sq;
    }
  }
  s2 += __shfl_down(s2, 16);
  s2 += __shfl_down(s2, 32);
  __shared__ float cs[128];
  __shared__ float s2w[4];
  if (tid < 128) cs[tid] = 0.f;
  if (l == 0) s2w[w] = s2;
  __syncthreads();
  atomicAdd(&cs[l16 * 4 + 0], c0.x); atomicAdd(&cs[l16 * 4 + 1], c0.y);
  atomicAdd(&cs[l16 * 4 + 2], c0.z); atomicAdd(&cs[l16 * 4 + 3], c0.w);
  atomicAdd(&cs[64 + l16 * 4 + 0], c1.x); atomicAdd(&cs[64 + l16 * 4 + 1], c1.y);
  atomicAdd(&cs[64 + l16 * 4 + 2], c1.z); atomicAdd(&cs[64 + l16 * 4 + 3], c1.w);
  __syncthreads();
  if (tid < 128) pSumX[blockIdx.x * 128 + tid] = cs[tid];
  if (tid == 0) pS2[blockIdx.x] = s2w[0] + s2w[1] + s2w[2] + s2w[3];
}

// ---------------------------------------------------------------------------
// merge_sums: 1 block x 1024 threads; 8-way segmented unrolled loads (MLP).
// ---------------------------------------------------------------------------
__global__ void merge_sums(const float* __restrict__ pSumX, const float* __restrict__ pS2,
                           float* __restrict__ sum_x, float* __restrict__ sum_nx2) {
  __shared__ float seg[8][128];
  __shared__ float s2w[4];
  const int t = threadIdx.x;       // 0..1023
  const int col = t & 127;
  const int sg = t >> 7;           // 0..7
  float s = 0.f;
#pragma unroll
  for (int b = 0; b < 32; ++b) s += pSumX[(sg * 32 + b) * 128 + col];
  seg[sg][col] = s;
  float s2 = (t < 256) ? pS2[t] : 0.f;
  if (t < 256) {
#pragma unroll
    for (int off = 32; off; off >>= 1) s2 += __shfl_down(s2, off);
    if ((t & 63) == 0) s2w[t >> 6] = s2;
  }
  __syncthreads();
  if (t < 128) {
    float r = 0.f;
#pragma unroll
    for (int k = 0; k < 8; ++k) r += seg[k][col];
    sum_x[t] = r;
  }
  if (t == 0) sum_nx2[0] = s2w[0] + s2w[1] + s2w[2] + s2w[3];
}

// ---------------------------------------------------------------------------
// prep_p: wave-per-row. Converts p->bf16; packs colc[j] =
// (Ac=(1+np2)*cfi, Bc=np2*cfi, np2, Tc=np2/(1+np2)); psiA[j] = psi.
// ---------------------------------------------------------------------------
__global__ void prep_p(const float* __restrict__ p, unsigned short* __restrict__ pb,
                       const float* __restrict__ sum_x, const float* __restrict__ sum_nx2,
                       float4* __restrict__ colc, float* __restrict__ psiA,
                       int M, int N) {
  const int lane = threadIdx.x & 63;
  const int wave = threadIdx.x >> 6;
  const int j = blockIdx.x * 4 + wave;
  if (j >= M) return;
  const float2* p2 = (const float2*)p;
  ushort2* pb2 = (ushort2*)pb;
  float2 v = p2[j * 64 + lane];
  ushort2 b;
  b.x = f2bf(v.x);
  b.y = f2bf(v.y);
  pb2[j * 64 + lane] = b;
  float np2 = fmaf(v.x, v.x, v.y * v.y);
  float sd = fmaf(v.x, sum_x[2 * lane], v.y * sum_x[2 * lane + 1]);
#pragma unroll
  for (int off = 32; off; off >>= 1) {
    np2 += __shfl_down(np2, off);
    sd += __shfl_down(sd, off);
  }
  if (lane == 0) {
    float ssd = *sum_nx2 + (float)N * np2 - 2.f * sd;
    float npn = sqrtf(np2);
    float cfi = 1.f / (npn * sqrtf(ssd));
    float4 cc;
    cc.x = (1.f + np2) * cfi;
    cc.y = np2 * cfi;
    cc.z = np2;
    cc.w = np2 / (1.f + np2);
    colc[j] = cc;
    psiA[j] = asinf(KCONST * (1.f - np2) / npn);
  }
}

// ---------------------------------------------------------------------------
// pair_mfma v4: R7 structure (full LDS staging of A+B via XOR-swizzled
// global_load_lds, exact early-out epilogue) + XCD-aware block swizzle.
// Grid is 1-D (2048); under round-robin dispatch (XCD = L % 8, learn_hip m09)
// each XCD owns rowTiles [16*xcd, 16*xcd+16) and walks all 16 colTiles ->
// per-XCD working set = 512 KB xb band + 512 KB pb, L2-resident, so the
// x16/x128 re-stage traffic is served at L2 speed instead of L3/HBM.
// Block partial folded into out via no-return atomicAdd (zeroed by prep_x).
// ---------------------------------------------------------------------------
__global__ __launch_bounds__(256, 2) void pair_mfma(
    const unsigned short* __restrict__ xb, const unsigned short* __restrict__ pb,
    const int* __restrict__ labels, const float* __restrict__ nx2p,
    const float4* __restrict__ colc, const float* __restrict__ psiA,
    float* __restrict__ out, float invN) {
  __shared__ float4 xs4[2048];  // 128 rows x 16 quads (quad = 8 bf16), swizzled
  __shared__ float4 ps4[2048];
  __shared__ float wred[4];

  const int L = blockIdx.x;
  const int xcd = L & 7;
  const int slot = L >> 3;                 // 0..255
  const int rowTile = xcd * 16 + (slot & 15);
  const int colTile = slot >> 4;           // 0..15
  const int row0 = rowTile * 128;
  const int col0 = colTile * 128;

  const int tid = threadIdx.x;
  const int l = tid & 63;
  const int w = tid >> 6;
  const float4* xg = (const float4*)(xb + (size_t)row0 * D_DIM);
  const float4* pg = (const float4*)(pb + (size_t)col0 * D_DIM);

  // stage A+B: LDS slot (r,ql) holds source quad (r, ql ^ (r&15))
#pragma unroll
  for (int ci = w; ci < 32; ci += 4) {
    int qi = ci * 64 + l;
    int r = qi >> 4, ql = qi & 15;
    int srcq = r * 16 + (ql ^ (r & 15));
    ASYNC_COPY16(xg + srcq, xs4 + ci * 64);
    ASYNC_COPY16(pg + srcq, ps4 + ci * 64);
  }
  __syncthreads();

  const int m = tid & 15;
  const int q = (tid >> 4) & 3;
  const int wr = (w & 1) * 64;   // wave's row offset within tile
  const int wc = (w >> 1) * 64;  // wave's col offset within tile

  f32x4 acc[4][4];
#pragma unroll
  for (int r = 0; r < 4; ++r)
#pragma unroll
    for (int c = 0; c < 4; ++c) acc[r][c] = (f32x4)(0.f);

#pragma unroll
  for (int s = 0; s < 4; ++s) {
    const int qphys = (s * 4 + q) ^ m;  // logical quad s*4+q at row low bits m
    bf16x8 a[4], b[4];
#pragma unroll
    for (int r = 0; r < 4; ++r) {
      a[r] = __builtin_bit_cast(bf16x8, xs4[(wr + r * 16 + m) * 16 + qphys]);
      b[r] = __builtin_bit_cast(bf16x8, ps4[(wc + r * 16 + m) * 16 + qphys]);
    }
#pragma unroll
    for (int r = 0; r < 4; ++r)
#pragma unroll
      for (int c = 0; c < 4; ++c)
        acc[r][c] = __builtin_amdgcn_mfma_f32_16x16x32_bf16(a[r], b[c], acc[r][c], 0, 0, 0);
  }

  // ---- fused epilogue with exact early-out ----
  float4 cc[4];
  int cols[4];
#pragma unroll
  for (int c = 0; c < 4; ++c) {
    cols[c] = col0 + wc + c * 16 + m;
    cc[c] = colc[cols[c]];  // (Ac, Bc, np2, Tc)
  }
  float4 rnp4v[4];
  int4 lb4v[4];
#pragma unroll
  for (int r = 0; r < 4; ++r) {
    rnp4v[r] = *(const float4*)&nx2p[row0 + wr + r * 16 + q * 4];  // 1+nx2
    lb4v[r] = *(const int4*)&labels[row0 + wr + r * 16 + q * 4];
  }

  float ssum = 0.f;
#pragma unroll
  for (int r = 0; r < 4; ++r) {
    const f32x4 rnp4 = __builtin_bit_cast(f32x4, rnp4v[r]);
    const int4 lb4 = lb4v[r];
#pragma unroll
    for (int c = 0; c < 4; ++c) {
      const f32x4 dv = acc[r][c];
      const float Tc = cc[c].w;
      // e_g > 0  <=>  nump_g > 0  (necessary for any neg contribution)
      float e0 = fmaf(-Tc, rnp4[0], dv[0]);
      float e1 = fmaf(-Tc, rnp4[1], dv[1]);
      float e2 = fmaf(-Tc, rnp4[2], dv[2]);
      float e3 = fmaf(-Tc, rnp4[3], dv[3]);
      float hm = fmaxf(fmaxf(e0, e1), fmaxf(e2, e3));
      bool h = (hm > 0.f) | (cols[c] == lb4.x) | (cols[c] == lb4.y) |
               (cols[c] == lb4.z) | (cols[c] == lb4.w);
      if (__builtin_expect(h, 0)) {
        const float psi = psiA[cols[c]];
        const float C1 = 1.f + psi;
        const float omnp2 = 1.f - cc[c].z;
#pragma unroll
        for (int g = 0; g < 4; ++g) {
          float rnp = rnp4[g];
          float dot = dv[g];
          int lb = (g == 0) ? lb4.x : (g == 1) ? lb4.y : (g == 2) ? lb4.z : lb4.w;
          float den2 = fmaf(cc[c].z, rnp, omnp2) - 2.f * dot;
          float nump = fmaf(dot, cc[c].x, -cc[c].y * rnp);
          float u = nump * __builtin_amdgcn_rsqf(den2);
          u = __builtin_amdgcn_fmed3f(u, -1.f, 1.f);
          float ax = fabsf(u);
          float rt = __builtin_amdgcn_sqrtf(1.f - ax);
          float poly = fmaf(fmaf(fmaf(-0.0187293f, ax, 0.0742610f), ax, -0.2121144f),
                            ax, 1.5707288f);
          float ac = rt * poly;
          ac = (u >= 0.f) ? ac : 3.14159265358979f - ac;
          float neg = __builtin_amdgcn_fmed3f(C1 - ac, 0.f, 1.f);
          float pos = fmaxf(0.f, ac - psi);
          ssum += (cols[c] == lb) ? pos : neg;
        }
      }
    }
  }

#pragma unroll
  for (int off = 32; off; off >>= 1) ssum += __shfl_down(ssum, off);
  if (l == 0) wred[w] = ssum;
  __syncthreads();
  if (tid == 0)
    atomicAdd(out, (wred[0] + wred[1] + wred[2] + wred[3]) * invN);
}

extern "C" void kernel_launch(void* const* d_in, const int* in_sizes, int n_in,
                              void* d_out, int out_size, void* d_ws, size_t ws_size,
                              hipStream_t stream) {
  const float* x = (const float*)d_in[0];
  const float* p = (const float*)d_in[1];
  const int* labels = (const int*)d_in[2];
  float* out = (float*)d_out;
  const int N = in_sizes[2];          // 16384
  const int M = in_sizes[1] / D_DIM;  // 2048

  float* ws = (float*)d_ws;
  float* nx2p = ws;                                  // N  (1 + ||x||^2)
  float4* colc = (float4*)(ws + N);                  // M float4
  float* psiA = ws + N + 4 * M;                      // M
  unsigned short* xb = (unsigned short*)(ws + N + 5 * M);            // N*128 bf16
  unsigned short* pb = (unsigned short*)(ws + N + 5 * M + 64 * N);   // M*128 bf16
  float* pSumX = ws + N + 5 * M + 64 * N + 64 * M;   // 256*128
  float* pS2 = pSumX + 256 * 128;                    // 256
  float* sum_x = pS2 + 256;                          // 128
  float* sum_nx2 = sum_x + 128;                      // 4

  prep_x<<<256, 256, 0, stream>>>(x, xb, nx2p, pSumX, pS2, out, N);
  merge_sums<<<1, 1024, 0, stream>>>(pSumX, pS2, sum_x, sum_nx2);
  prep_p<<<M / 4, 256, 0, stream>>>(p, pb, sum_x, sum_nx2, colc, psiA, M, N);

  pair_mfma<<<2048, 256, 0, stream>>>(xb, pb, labels, nx2p, colc, psiA, out,
                                      1.0f / (float)N);
}

// Round 11
// 94.230 us; speedup vs baseline: 1.2227x; 1.0955x over previous
//
#include <hip/hip_runtime.h>
#include <math.h>

#define KCONST 0.1f
#define GAMMA_C 1.0f
#define D_DIM 128

typedef __attribute__((ext_vector_type(8))) short bf16x8;
typedef __attribute__((ext_vector_type(4))) float f32x4;

#define ASYNC_COPY16(gsrc, ldst)                                                  \
  __builtin_amdgcn_global_load_lds(                                               \
      (const __attribute__((address_space(1))) void*)(gsrc),                      \
      (__attribute__((address_space(3))) void*)(ldst), 16, 0, 0)

__device__ __forceinline__ unsigned short f2bf(float f) {
  unsigned int u = __float_as_uint(f);
  u += 0x7fffu + ((u >> 16) & 1u);  // round-to-nearest-even
  return (unsigned short)(u >> 16);
}

// ---------------------------------------------------------------------------
// prep_x: 256 blocks. Converts x->bf16, writes nx2p[row]=1+||x||^2, per-block
// partial col-sums + sum(nx2).
// ---------------------------------------------------------------------------
__global__ void prep_x(const float* __restrict__ x, unsigned short* __restrict__ xb,
                       float* __restrict__ nx2p, float* __restrict__ pSumX,
                       float* __restrict__ pS2, int N) {
  const int tid = threadIdx.x;
  const int l = tid & 63, w = tid >> 6;
  const int l16 = l & 15, sub = l >> 4;
  const int waveId = blockIdx.x * 4 + w;  // 0..1023
  const float4* x4 = (const float4*)x;
  ushort4* xb4 = (ushort4*)xb;
  float4 c0 = {0.f, 0.f, 0.f, 0.f}, c1 = {0.f, 0.f, 0.f, 0.f};
  float s2 = 0.f;
#pragma unroll
  for (int it = 0; it < 4; ++it) {
    int row = (waveId + it * 1024) * 4 + sub;
    float4 v0 = x4[row * 32 + l16];
    float4 v1 = x4[row * 32 + 16 + l16];
    c0.x += v0.x; c0.y += v0.y; c0.z += v0.z; c0.w += v0.w;
    c1.x += v1.x; c1.y += v1.y; c1.z += v1.z; c1.w += v1.w;
    ushort4 b0, b1;
    b0.x = f2bf(v0.x); b0.y = f2bf(v0.y); b0.z = f2bf(v0.z); b0.w = f2bf(v0.w);
    b1.x = f2bf(v1.x); b1.y = f2bf(v1.y); b1.z = f2bf(v1.z); b1.w = f2bf(v1.w);
    xb4[row * 32 + l16] = b0;
    xb4[row * 32 + 16 + l16] = b1;
    float sq = v0.x * v0.x;
    sq = fmaf(v0.y, v0.y, sq); sq = fmaf(v0.z, v0.z, sq); sq = fmaf(v0.w, v0.w, sq);
    sq = fmaf(v1.x, v1.x, sq); sq = fmaf(v1.y, v1.y, sq);
    sq = fmaf(v1.z, v1.z, sq); sq = fmaf(v1.w, v1.w, sq);
    sq += __shfl_down(sq, 8); sq += __shfl_down(sq, 4);
    sq += __shfl_down(sq, 2); sq += __shfl_down(sq, 1);
    if (l16 == 0) {
      nx2p[row] = 1.f + sq;
      s2 += sq;
    }
  }
  s2 += __shfl_down(s2, 16);
  s2 += __shfl_down(s2, 32);
  __shared__ float cs[128];
  __shared__ float s2w[4];
  if (tid < 128) cs[tid] = 0.f;
  if (l == 0) s2w[w] = s2;
  __syncthreads();
  atomicAdd(&cs[l16 * 4 + 0], c0.x); atomicAdd(&cs[l16 * 4 + 1], c0.y);
  atomicAdd(&cs[l16 * 4 + 2], c0.z); atomicAdd(&cs[l16 * 4 + 3], c0.w);
  atomicAdd(&cs[64 + l16 * 4 + 0], c1.x); atomicAdd(&cs[64 + l16 * 4 + 1], c1.y);
  atomicAdd(&cs[64 + l16 * 4 + 2], c1.z); atomicAdd(&cs[64 + l16 * 4 + 3], c1.w);
  __syncthreads();
  if (tid < 128) pSumX[blockIdx.x * 128 + tid] = cs[tid];
  if (tid == 0) pS2[blockIdx.x] = s2w[0] + s2w[1] + s2w[2] + s2w[3];
}

// ---------------------------------------------------------------------------
// merge_sums: 1 block x 1024 threads; 8-way segmented unrolled loads (MLP).
// ---------------------------------------------------------------------------
__global__ void merge_sums(const float* __restrict__ pSumX, const float* __restrict__ pS2,
                           float* __restrict__ sum_x, float* __restrict__ sum_nx2) {
  __shared__ float seg[8][128];
  __shared__ float s2w[4];
  const int t = threadIdx.x;       // 0..1023
  const int col = t & 127;
  const int sg = t >> 7;           // 0..7
  float s = 0.f;
#pragma unroll
  for (int b = 0; b < 32; ++b) s += pSumX[(sg * 32 + b) * 128 + col];
  seg[sg][col] = s;
  float s2 = (t < 256) ? pS2[t] : 0.f;
  if (t < 256) {
#pragma unroll
    for (int off = 32; off; off >>= 1) s2 += __shfl_down(s2, off);
    if ((t & 63) == 0) s2w[t >> 6] = s2;
  }
  __syncthreads();
  if (t < 128) {
    float r = 0.f;
#pragma unroll
    for (int k = 0; k < 8; ++k) r += seg[k][col];
    sum_x[t] = r;
  }
  if (t == 0) sum_nx2[0] = s2w[0] + s2w[1] + s2w[2] + s2w[3];
}

// ---------------------------------------------------------------------------
// prep_p: wave-per-row. Converts p->bf16; packs colc[j] =
// (Ac=(1+np2)*cfi, Bc=np2*cfi, np2, Tc=np2/(1+np2)); psiA[j] = psi.
// ---------------------------------------------------------------------------
__global__ void prep_p(const float* __restrict__ p, unsigned short* __restrict__ pb,
                       const float* __restrict__ sum_x, const float* __restrict__ sum_nx2,
                       float4* __restrict__ colc, float* __restrict__ psiA,
                       int M, int N) {
  const int lane = threadIdx.x & 63;
  const int wave = threadIdx.x >> 6;
  const int j = blockIdx.x * 4 + wave;
  if (j >= M) return;
  const float2* p2 = (const float2*)p;
  ushort2* pb2 = (ushort2*)pb;
  float2 v = p2[j * 64 + lane];
  ushort2 b;
  b.x = f2bf(v.x);
  b.y = f2bf(v.y);
  pb2[j * 64 + lane] = b;
  float np2 = fmaf(v.x, v.x, v.y * v.y);
  float sd = fmaf(v.x, sum_x[2 * lane], v.y * sum_x[2 * lane + 1]);
#pragma unroll
  for (int off = 32; off; off >>= 1) {
    np2 += __shfl_down(np2, off);
    sd += __shfl_down(sd, off);
  }
  if (lane == 0) {
    float ssd = *sum_nx2 + (float)N * np2 - 2.f * sd;
    float npn = sqrtf(np2);
    float cfi = 1.f / (npn * sqrtf(ssd));
    float4 cc;
    cc.x = (1.f + np2) * cfi;
    cc.y = np2 * cfi;
    cc.z = np2;
    cc.w = np2 / (1.f + np2);
    colc[j] = cc;
    psiA[j] = asinf(KCONST * (1.f - np2) / npn);
  }
}

// ---------------------------------------------------------------------------
// pair_mfma v5: tile-loop pipeline. 512 blocks; block b owns rowTile b>>2
// (128 rows; xs 32 KB staged ONCE) and walks 8 colTiles of 64 cols
// (ps double-buffered 2x16 KB). Per iter: one barrier (drains only the
// prefetch issued LAST iter, which had a full compute phase to land),
// then issue next prefetch, then 32 MFMA/wave + fused early-out epilogue.
// LDS 64 KB -> 2 blocks/CU. Row-side constants hoisted out of the loop.
// ---------------------------------------------------------------------------
__global__ __launch_bounds__(256, 2) void pair_mfma(
    const unsigned short* __restrict__ xb, const unsigned short* __restrict__ pb,
    const int* __restrict__ labels, const float* __restrict__ nx2p,
    const float4* __restrict__ colc, const float* __restrict__ psiA,
    float* __restrict__ partials) {
  __shared__ float4 xs4[2048];     // 128 rows x 16 quads (swizzled)
  __shared__ float4 ps4[2][1024];  // 2 x (64 rows x 16 quads, swizzled)
  __shared__ float wred[4];

  const int b = blockIdx.x;
  const int rowTile = b >> 2;   // 0..127
  const int cg = b & 3;         // colGroup: colTiles cg*8 .. cg*8+7
  const int row0 = rowTile * 128;

  const int tid = threadIdx.x;
  const int l = tid & 63;
  const int w = tid >> 6;
  const float4* xg = (const float4*)(xb + (size_t)row0 * D_DIM);

  // stage xs once: slot (r,ql) <- source quad (r, ql ^ (r&15))
#pragma unroll
  for (int ci = w; ci < 32; ci += 4) {
    int qi = ci * 64 + l;
    int r = qi >> 4, ql = qi & 15;
    ASYNC_COPY16(xg + r * 16 + (ql ^ (r & 15)), xs4 + ci * 64);
  }
  // stage ps[0] for colTile cg*8
  {
    const float4* pg = (const float4*)(pb + (size_t)(cg * 8) * 64 * D_DIM);
#pragma unroll
    for (int ci = w; ci < 16; ci += 4) {
      int qi = ci * 64 + l;
      int r = qi >> 4, ql = qi & 15;
      ASYNC_COPY16(pg + r * 16 + (ql ^ (r & 15)), ps4[0] + ci * 64);
    }
  }

  const int m = tid & 15;
  const int q = (tid >> 4) & 3;
  const int wr = (w & 1) * 64;   // wave's row offset (64 rows)
  const int wc = (w >> 1) * 32;  // wave's col offset (32 cols)

  // row-side constants: fixed across all 8 tile-iterations
  f32x4 rnp4v[4];
  int4 lb4v[4];
#pragma unroll
  for (int r = 0; r < 4; ++r) {
    rnp4v[r] = __builtin_bit_cast(f32x4, *(const float4*)&nx2p[row0 + wr + r * 16 + q * 4]);
    lb4v[r] = *(const int4*)&labels[row0 + wr + r * 16 + q * 4];
  }

  float ssum = 0.f;
  for (int it = 0; it < 8; ++it) {
    __syncthreads();  // vmcnt(0) drain = the prefetch issued last iter (ready)
    const int cur = it & 1;
    if (it < 7) {  // prefetch next colTile into the other buffer
      const float4* pg = (const float4*)(pb + (size_t)(cg * 8 + it + 1) * 64 * D_DIM);
#pragma unroll
      for (int ci = w; ci < 16; ci += 4) {
        int qi = ci * 64 + l;
        int r = qi >> 4, ql = qi & 15;
        ASYNC_COPY16(pg + r * 16 + (ql ^ (r & 15)), ps4[cur ^ 1] + ci * 64);
      }
    }

    // ---- compute 128x64 tile: 4x2 frags/wave, 4 k-steps ----
    f32x4 acc[4][2];
#pragma unroll
    for (int r = 0; r < 4; ++r) {
      acc[r][0] = (f32x4)(0.f);
      acc[r][1] = (f32x4)(0.f);
    }
#pragma unroll
    for (int s = 0; s < 4; ++s) {
      const int qphys = (s * 4 + q) ^ m;
      bf16x8 a[4], bf[2];
#pragma unroll
      for (int c = 0; c < 2; ++c)
        bf[c] = __builtin_bit_cast(bf16x8, ps4[cur][(wc + c * 16 + m) * 16 + qphys]);
#pragma unroll
      for (int r = 0; r < 4; ++r)
        a[r] = __builtin_bit_cast(bf16x8, xs4[(wr + r * 16 + m) * 16 + qphys]);
#pragma unroll
      for (int r = 0; r < 4; ++r)
#pragma unroll
        for (int c = 0; c < 2; ++c)
          acc[r][c] = __builtin_amdgcn_mfma_f32_16x16x32_bf16(a[r], bf[c], acc[r][c], 0, 0, 0);
    }

    // ---- fused epilogue with exact early-out ----
    const int ct0 = (cg * 8 + it) * 64;
#pragma unroll
    for (int c = 0; c < 2; ++c) {
      const int col = ct0 + wc + c * 16 + m;
      const float4 cc = colc[col];  // (Ac, Bc, np2, Tc)
      const float Tc = cc.w;
#pragma unroll
      for (int r = 0; r < 4; ++r) {
        const f32x4 rnp4 = rnp4v[r];
        const int4 lb4 = lb4v[r];
        const f32x4 dv = acc[r][c];
        float e0 = fmaf(-Tc, rnp4[0], dv[0]);
        float e1 = fmaf(-Tc, rnp4[1], dv[1]);
        float e2 = fmaf(-Tc, rnp4[2], dv[2]);
        float e3 = fmaf(-Tc, rnp4[3], dv[3]);
        float hm = fmaxf(fmaxf(e0, e1), fmaxf(e2, e3));
        bool h = (hm > 0.f) | (col == lb4.x) | (col == lb4.y) |
                 (col == lb4.z) | (col == lb4.w);
        if (__builtin_expect(h, 0)) {
          const float psi = psiA[col];
          const float C1 = 1.f + psi;
          const float omnp2 = 1.f - cc.z;
#pragma unroll
          for (int g = 0; g < 4; ++g) {
            float rnp = rnp4[g];
            float dot = dv[g];
            int lb = (g == 0) ? lb4.x : (g == 1) ? lb4.y : (g == 2) ? lb4.z : lb4.w;
            float den2 = fmaf(cc.z, rnp, omnp2) - 2.f * dot;
            float nump = fmaf(dot, cc.x, -cc.y * rnp);
            float u = nump * __builtin_amdgcn_rsqf(den2);
            u = __builtin_amdgcn_fmed3f(u, -1.f, 1.f);
            float ax = fabsf(u);
            float rt = __builtin_amdgcn_sqrtf(1.f - ax);
            float poly = fmaf(fmaf(fmaf(-0.0187293f, ax, 0.0742610f), ax, -0.2121144f),
                              ax, 1.5707288f);
            float ac = rt * poly;
            ac = (u >= 0.f) ? ac : 3.14159265358979f - ac;
            float neg = __builtin_amdgcn_fmed3f(C1 - ac, 0.f, 1.f);
            float pos = fmaxf(0.f, ac - psi);
            ssum += (col == lb) ? pos : neg;
          }
        }
      }
    }
  }

#pragma unroll
  for (int off = 32; off; off >>= 1) ssum += __shfl_down(ssum, off);
  if (l == 0) wred[w] = ssum;
  __syncthreads();
  if (tid == 0)
    partials[b] = wred[0] + wred[1] + wred[2] + wred[3];
}

// ---------------------------------------------------------------------------
// finalize: reduce the 512 pair partials, scale by 1/N.
// ---------------------------------------------------------------------------
__global__ void finalize(const float* __restrict__ partials, float* __restrict__ out,
                         int n, float invN) {
  float s = 0.f;
  for (int i = threadIdx.x; i < n; i += 256) s += partials[i];
#pragma unroll
  for (int off = 32; off; off >>= 1) s += __shfl_down(s, off);
  __shared__ float wred[4];
  if ((threadIdx.x & 63) == 0) wred[threadIdx.x >> 6] = s;
  __syncthreads();
  if (threadIdx.x == 0) out[0] = (wred[0] + wred[1] + wred[2] + wred[3]) * invN;
}

extern "C" void kernel_launch(void* const* d_in, const int* in_sizes, int n_in,
                              void* d_out, int out_size, void* d_ws, size_t ws_size,
                              hipStream_t stream) {
  const float* x = (const float*)d_in[0];
  const float* p = (const float*)d_in[1];
  const int* labels = (const int*)d_in[2];
  float* out = (float*)d_out;
  const int N = in_sizes[2];          // 16384
  const int M = in_sizes[1] / D_DIM;  // 2048

  float* ws = (float*)d_ws;
  float* nx2p = ws;                                  // N  (1 + ||x||^2)
  float4* colc = (float4*)(ws + N);                  // M float4
  float* psiA = ws + N + 4 * M;                      // M
  unsigned short* xb = (unsigned short*)(ws + N + 5 * M);            // N*128 bf16
  unsigned short* pb = (unsigned short*)(ws + N + 5 * M + 64 * N);   // M*128 bf16
  float* pSumX = ws + N + 5 * M + 64 * N + 64 * M;   // 256*128
  float* pS2 = pSumX + 256 * 128;                    // 256
  float* sum_x = pS2 + 256;                          // 128
  float* sum_nx2 = sum_x + 128;                      // 4
  float* partials = sum_nx2 + 4;                     // 512

  prep_x<<<256, 256, 0, stream>>>(x, xb, nx2p, pSumX, pS2, N);
  merge_sums<<<1, 1024, 0, stream>>>(pSumX, pS2, sum_x, sum_nx2);
  prep_p<<<M / 4, 256, 0, stream>>>(p, pb, sum_x, sum_nx2, colc, psiA, M, N);

  pair_mfma<<<512, 256, 0, stream>>>(xb, pb, labels, nx2p, colc, psiA, partials);

  finalize<<<1, 256, 0, stream>>>(partials, out, 512, 1.0f / (float)N);
}

// Round 12
// 92.998 us; speedup vs baseline: 1.2389x; 1.0132x over previous
//
#include <hip/hip_runtime.h>
#include <math.h>

#define KCONST 0.1f
#define GAMMA_C 1.0f
#define D_DIM 128

typedef __attribute__((ext_vector_type(8))) short bf16x8;
typedef __attribute__((ext_vector_type(4))) float f32x4;

#define ASYNC_COPY16(gsrc, ldst)                                                  \
  __builtin_amdgcn_global_load_lds(                                               \
      (const __attribute__((address_space(1))) void*)(gsrc),                      \
      (__attribute__((address_space(3))) void*)(ldst), 16, 0, 0)

__device__ __forceinline__ unsigned short f2bf(float f) {
  unsigned int u = __float_as_uint(f);
  u += 0x7fffu + ((u >> 16) & 1u);  // round-to-nearest-even
  return (unsigned short)(u >> 16);
}

// ---------------------------------------------------------------------------
// prep_x: 256 blocks. Converts x->bf16, writes nx2p[row]=1+||x||^2, per-block
// partial col-sums + sum(nx2). Block 0 zeroes out[0].
// ---------------------------------------------------------------------------
__global__ void prep_x(const float* __restrict__ x, unsigned short* __restrict__ xb,
                       float* __restrict__ nx2p, float* __restrict__ pSumX,
                       float* __restrict__ pS2, float* __restrict__ out_zero, int N) {
  if (blockIdx.x == 0 && threadIdx.x == 0) *out_zero = 0.f;
  const int tid = threadIdx.x;
  const int l = tid & 63, w = tid >> 6;
  const int l16 = l & 15, sub = l >> 4;
  const int waveId = blockIdx.x * 4 + w;  // 0..1023
  const float4* x4 = (const float4*)x;
  ushort4* xb4 = (ushort4*)xb;
  float4 c0 = {0.f, 0.f, 0.f, 0.f}, c1 = {0.f, 0.f, 0.f, 0.f};
  float s2 = 0.f;
#pragma unroll
  for (int it = 0; it < 4; ++it) {
    int row = (waveId + it * 1024) * 4 + sub;
    float4 v0 = x4[row * 32 + l16];
    float4 v1 = x4[row * 32 + 16 + l16];
    c0.x += v0.x; c0.y += v0.y; c0.z += v0.z; c0.w += v0.w;
    c1.x += v1.x; c1.y += v1.y; c1.z += v1.z; c1.w += v1.w;
    ushort4 b0, b1;
    b0.x = f2bf(v0.x); b0.y = f2bf(v0.y); b0.z = f2bf(v0.z); b0.w = f2bf(v0.w);
    b1.x = f2bf(v1.x); b1.y = f2bf(v1.y); b1.z = f2bf(v1.z); b1.w = f2bf(v1.w);
    xb4[row * 32 + l16] = b0;
    xb4[row * 32 + 16 + l16] = b1;
    float sq = v0.x * v0.x;
    sq = fmaf(v0.y, v0.y, sq); sq = fmaf(v0.z, v0.z, sq); sq = fmaf(v0.w, v0.w, sq);
    sq = fmaf(v1.x, v1.x, sq); sq = fmaf(v1.y, v1.y, sq);
    sq = fmaf(v1.z, v1.z, sq); sq = fmaf(v1.w, v1.w, sq);
    sq += __shfl_down(sq, 8); sq += __shfl_down(sq, 4);
    sq += __shfl_down(sq, 2); sq += __shfl_down(sq, 1);
    if (l16 == 0) {
      nx2p[row] = 1.f + sq;
      s2 += sq;
    }
  }
  s2 += __shfl_down(s2, 16);
  s2 += __shfl_down(s2, 32);
  __shared__ float cs[128];
  __shared__ float s2w[4];
  if (tid < 128) cs[tid] = 0.f;
  if (l == 0) s2w[w] = s2;
  __syncthreads();
  atomicAdd(&cs[l16 * 4 + 0], c0.x); atomicAdd(&cs[l16 * 4 + 1], c0.y);
  atomicAdd(&cs[l16 * 4 + 2], c0.z); atomicAdd(&cs[l16 * 4 + 3], c0.w);
  atomicAdd(&cs[64 + l16 * 4 + 0], c1.x); atomicAdd(&cs[64 + l16 * 4 + 1], c1.y);
  atomicAdd(&cs[64 + l16 * 4 + 2], c1.z); atomicAdd(&cs[64 + l16 * 4 + 3], c1.w);
  __syncthreads();
  if (tid < 128) pSumX[blockIdx.x * 128 + tid] = cs[tid];
  if (tid == 0) pS2[blockIdx.x] = s2w[0] + s2w[1] + s2w[2] + s2w[3];
}

// ---------------------------------------------------------------------------
// merge_sums: 1 block x 1024 threads; 8-way segmented unrolled loads (MLP).
// ---------------------------------------------------------------------------
__global__ void merge_sums(const float* __restrict__ pSumX, const float* __restrict__ pS2,
                           float* __restrict__ sum_x, float* __restrict__ sum_nx2) {
  __shared__ float seg[8][128];
  __shared__ float s2w[4];
  const int t = threadIdx.x;       // 0..1023
  const int col = t & 127;
  const int sg = t >> 7;           // 0..7
  float s = 0.f;
#pragma unroll
  for (int b = 0; b < 32; ++b) s += pSumX[(sg * 32 + b) * 128 + col];
  seg[sg][col] = s;
  float s2 = (t < 256) ? pS2[t] : 0.f;
  if (t < 256) {
#pragma unroll
    for (int off = 32; off; off >>= 1) s2 += __shfl_down(s2, off);
    if ((t & 63) == 0) s2w[t >> 6] = s2;
  }
  __syncthreads();
  if (t < 128) {
    float r = 0.f;
#pragma unroll
    for (int k = 0; k < 8; ++k) r += seg[k][col];
    sum_x[t] = r;
  }
  if (t == 0) sum_nx2[0] = s2w[0] + s2w[1] + s2w[2] + s2w[3];
}

// ---------------------------------------------------------------------------
// prep_p: wave-per-row. Converts p->bf16; packs colc[j] =
// (Ac=(1+np2)*cfi, Bc=np2*cfi, np2, Tc=np2/(1+np2)); psiA[j] = psi.
// ---------------------------------------------------------------------------
__global__ void prep_p(const float* __restrict__ p, unsigned short* __restrict__ pb,
                       const float* __restrict__ sum_x, const float* __restrict__ sum_nx2,
                       float4* __restrict__ colc, float* __restrict__ psiA,
                       int M, int N) {
  const int lane = threadIdx.x & 63;
  const int wave = threadIdx.x >> 6;
  const int j = blockIdx.x * 4 + wave;
  if (j >= M) return;
  const float2* p2 = (const float2*)p;
  ushort2* pb2 = (ushort2*)pb;
  float2 v = p2[j * 64 + lane];
  ushort2 b;
  b.x = f2bf(v.x);
  b.y = f2bf(v.y);
  pb2[j * 64 + lane] = b;
  float np2 = fmaf(v.x, v.x, v.y * v.y);
  float sd = fmaf(v.x, sum_x[2 * lane], v.y * sum_x[2 * lane + 1]);
#pragma unroll
  for (int off = 32; off; off >>= 1) {
    np2 += __shfl_down(np2, off);
    sd += __shfl_down(sd, off);
  }
  if (lane == 0) {
    float ssd = *sum_nx2 + (float)N * np2 - 2.f * sd;
    float npn = sqrtf(np2);
    float cfi = 1.f / (npn * sqrtf(ssd));
    float4 cc;
    cc.x = (1.f + np2) * cfi;
    cc.y = np2 * cfi;
    cc.z = np2;
    cc.w = np2 / (1.f + np2);
    colc[j] = cc;
    psiA[j] = asinf(KCONST * (1.f - np2) / npn);
  }
}

// ---------------------------------------------------------------------------
// pair_mfma v6: v5 tile-loop pipeline + (a) fully-unrolled it-loop (static
// LDS buffer indices -> cross-iter scheduling), (b) register software-
// prefetch of next iter's colc quads (hides the ~200cyc L2 latency that sat
// on the hit-test critical path), (c) block partial folded into out via one
// atomicAdd (finalize kernel removed; out zeroed by prep_x).
// 512 blocks; block b: rowTile b>>2 (xs 32 KB staged once), walks 8 colTiles
// of 64 cols (ps 2x16 KB double-buffer). LDS 64 KB -> 2 blocks/CU.
// ---------------------------------------------------------------------------
__global__ __launch_bounds__(256, 2) void pair_mfma(
    const unsigned short* __restrict__ xb, const unsigned short* __restrict__ pb,
    const int* __restrict__ labels, const float* __restrict__ nx2p,
    const float4* __restrict__ colc, const float* __restrict__ psiA,
    float* __restrict__ out, float invN) {
  __shared__ float4 xs4[2048];     // 128 rows x 16 quads (swizzled)
  __shared__ float4 ps4[2][1024];  // 2 x (64 rows x 16 quads, swizzled)
  __shared__ float wred[4];

  const int b = blockIdx.x;
  const int rowTile = b >> 2;   // 0..127
  const int cg = b & 3;         // colGroup: colTiles cg*8 .. cg*8+7
  const int row0 = rowTile * 128;

  const int tid = threadIdx.x;
  const int l = tid & 63;
  const int w = tid >> 6;
  const float4* xg = (const float4*)(xb + (size_t)row0 * D_DIM);

  // stage xs once: slot (r,ql) <- source quad (r, ql ^ (r&15))
#pragma unroll
  for (int ci = w; ci < 32; ci += 4) {
    int qi = ci * 64 + l;
    int r = qi >> 4, ql = qi & 15;
    ASYNC_COPY16(xg + r * 16 + (ql ^ (r & 15)), xs4 + ci * 64);
  }
  // stage ps[0] for colTile cg*8
  {
    const float4* pg = (const float4*)(pb + (size_t)(cg * 8) * 64 * D_DIM);
#pragma unroll
    for (int ci = w; ci < 16; ci += 4) {
      int qi = ci * 64 + l;
      int r = qi >> 4, ql = qi & 15;
      ASYNC_COPY16(pg + r * 16 + (ql ^ (r & 15)), ps4[0] + ci * 64);
    }
  }

  const int m = tid & 15;
  const int q = (tid >> 4) & 3;
  const int wr = (w & 1) * 64;   // wave's row offset (64 rows)
  const int wc = (w >> 1) * 32;  // wave's col offset (32 cols)

  // row-side constants: fixed across all 8 tile-iterations
  f32x4 rnp4v[4];
  int4 lb4v[4];
#pragma unroll
  for (int r = 0; r < 4; ++r) {
    rnp4v[r] = __builtin_bit_cast(f32x4, *(const float4*)&nx2p[row0 + wr + r * 16 + q * 4]);
    lb4v[r] = *(const int4*)&labels[row0 + wr + r * 16 + q * 4];
  }

  // register-prefetch colc for iter 0 (coalesced 256B segment per load)
  float4 ccur0 = colc[(cg * 8) * 64 + wc + m];
  float4 ccur1 = colc[(cg * 8) * 64 + wc + 16 + m];

  float ssum = 0.f;
#pragma unroll
  for (int it = 0; it < 8; ++it) {
    __syncthreads();  // drains the ps prefetch issued last iter (landed)
    const int cur = it & 1;
    if (it < 7) {  // prefetch next colTile into the other buffer
      const float4* pg = (const float4*)(pb + (size_t)(cg * 8 + it + 1) * 64 * D_DIM);
#pragma unroll
      for (int ci = w; ci < 16; ci += 4) {
        int qi = ci * 64 + l;
        int r = qi >> 4, ql = qi & 15;
        ASYNC_COPY16(pg + r * 16 + (ql ^ (r & 15)), ps4[cur ^ 1] + ci * 64);
      }
    }
    // register-prefetch next iter's colc (latency hidden under compute below)
    float4 cnext0, cnext1;
    if (it < 7) {
      cnext0 = colc[(cg * 8 + it + 1) * 64 + wc + m];
      cnext1 = colc[(cg * 8 + it + 1) * 64 + wc + 16 + m];
    }

    // ---- compute 128x64 tile: 4x2 frags/wave, 4 k-steps ----
    f32x4 acc[4][2];
#pragma unroll
    for (int r = 0; r < 4; ++r) {
      acc[r][0] = (f32x4)(0.f);
      acc[r][1] = (f32x4)(0.f);
    }
#pragma unroll
    for (int s = 0; s < 4; ++s) {
      const int qphys = (s * 4 + q) ^ m;
      bf16x8 a[4], bf[2];
#pragma unroll
      for (int c = 0; c < 2; ++c)
        bf[c] = __builtin_bit_cast(bf16x8, ps4[cur][(wc + c * 16 + m) * 16 + qphys]);
#pragma unroll
      for (int r = 0; r < 4; ++r)
        a[r] = __builtin_bit_cast(bf16x8, xs4[(wr + r * 16 + m) * 16 + qphys]);
#pragma unroll
      for (int r = 0; r < 4; ++r)
#pragma unroll
        for (int c = 0; c < 2; ++c)
          acc[r][c] = __builtin_amdgcn_mfma_f32_16x16x32_bf16(a[r], bf[c], acc[r][c], 0, 0, 0);
    }

    // ---- fused epilogue with exact early-out ----
    const int ct0 = (cg * 8 + it) * 64;
#pragma unroll
    for (int c = 0; c < 2; ++c) {
      const int col = ct0 + wc + c * 16 + m;
      const float4 cc = (c == 0) ? ccur0 : ccur1;  // (Ac, Bc, np2, Tc)
      const float Tc = cc.w;
#pragma unroll
      for (int r = 0; r < 4; ++r) {
        const f32x4 rnp4 = rnp4v[r];
        const int4 lb4 = lb4v[r];
        const f32x4 dv = acc[r][c];
        float e0 = fmaf(-Tc, rnp4[0], dv[0]);
        float e1 = fmaf(-Tc, rnp4[1], dv[1]);
        float e2 = fmaf(-Tc, rnp4[2], dv[2]);
        float e3 = fmaf(-Tc, rnp4[3], dv[3]);
        float hm = fmaxf(fmaxf(e0, e1), fmaxf(e2, e3));
        bool h = (hm > 0.f) | (col == lb4.x) | (col == lb4.y) |
                 (col == lb4.z) | (col == lb4.w);
        if (__builtin_expect(h, 0)) {
          const float psi = psiA[col];
          const float C1 = 1.f + psi;
          const float omnp2 = 1.f - cc.z;
#pragma unroll
          for (int g = 0; g < 4; ++g) {
            float rnp = rnp4[g];
            float dot = dv[g];
            int lb = (g == 0) ? lb4.x : (g == 1) ? lb4.y : (g == 2) ? lb4.z : lb4.w;
            float den2 = fmaf(cc.z, rnp, omnp2) - 2.f * dot;
            float nump = fmaf(dot, cc.x, -cc.y * rnp);
            float u = nump * __builtin_amdgcn_rsqf(den2);
            u = __builtin_amdgcn_fmed3f(u, -1.f, 1.f);
            float ax = fabsf(u);
            float rt = __builtin_amdgcn_sqrtf(1.f - ax);
            float poly = fmaf(fmaf(fmaf(-0.0187293f, ax, 0.0742610f), ax, -0.2121144f),
                              ax, 1.5707288f);
            float ac = rt * poly;
            ac = (u >= 0.f) ? ac : 3.14159265358979f - ac;
            float neg = __builtin_amdgcn_fmed3f(C1 - ac, 0.f, 1.f);
            float pos = fmaxf(0.f, ac - psi);
            ssum += (col == lb) ? pos : neg;
          }
        }
      }
    }
    if (it < 7) {
      ccur0 = cnext0;
      ccur1 = cnext1;
    }
  }

#pragma unroll
  for (int off = 32; off; off >>= 1) ssum += __shfl_down(ssum, off);
  if (l == 0) wred[w] = ssum;
  __syncthreads();
  if (tid == 0)
    atomicAdd(out, (wred[0] + wred[1] + wred[2] + wred[3]) * invN);
}

extern "C" void kernel_launch(void* const* d_in, const int* in_sizes, int n_in,
                              void* d_out, int out_size, void* d_ws, size_t ws_size,
                              hipStream_t stream) {
  const float* x = (const float*)d_in[0];
  const float* p = (const float*)d_in[1];
  const int* labels = (const int*)d_in[2];
  float* out = (float*)d_out;
  const int N = in_sizes[2];          // 16384
  const int M = in_sizes[1] / D_DIM;  // 2048

  float* ws = (float*)d_ws;
  float* nx2p = ws;                                  // N  (1 + ||x||^2)
  float4* colc = (float4*)(ws + N);                  // M float4
  float* psiA = ws + N + 4 * M;                      // M
  unsigned short* xb = (unsigned short*)(ws + N + 5 * M);            // N*128 bf16
  unsigned short* pb = (unsigned short*)(ws + N + 5 * M + 64 * N);   // M*128 bf16
  float* pSumX = ws + N + 5 * M + 64 * N + 64 * M;   // 256*128
  float* pS2 = pSumX + 256 * 128;                    // 256
  float* sum_x = pS2 + 256;                          // 128
  float* sum_nx2 = sum_x + 128;                      // 4

  prep_x<<<256, 256, 0, stream>>>(x, xb, nx2p, pSumX, pS2, out, N);
  merge_sums<<<1, 1024, 0, stream>>>(pSumX, pS2, sum_x, sum_nx2);
  prep_p<<<M / 4, 256, 0, stream>>>(p, pb, sum_x, sum_nx2, colc, psiA, M, N);

  pair_mfma<<<512, 256, 0, stream>>>(xb, pb, labels, nx2p, colc, psiA, out,
                                     1.0f / (float)N);
}